// Round 4
// baseline (185.211 us; speedup 1.0000x reference)
//
#include <hip/hip_runtime.h>
#include <math.h>

#define CC 512
#define HH 64
#define WW 96
#define NN 16
#define HW (HH*WW)        // 6144
#define NA 9
#define NLOC 36
#define NSC 18

// Balanced output groups per wave: {14, 14, 14, 12}
//   g0: o 0..13   (loc 0..13)
//   g1: o 14..27  (loc 14..27)
//   g2: o 28..41  (loc 28..35 + score 0..5)
//   g3: o 42..53  (score 6..17)
// wT3 layout: group g base = g*CC*16 floats; row c = 16 floats (64B aligned)
#define GSTRIDE 16

// ---------------------------------------------------------------------------
// Kernel 1: scatter weights into padded per-group transposed layout.
// ---------------------------------------------------------------------------
__global__ void transpose_w_kernel(const float* __restrict__ lw,
                                   const float* __restrict__ sw,
                                   float* __restrict__ wT3) {
    int i = blockIdx.x * 256 + threadIdx.x;   // over CC*54
    if (i >= CC * 54) return;
    int c = i / 54, o = i % 54;
    int g = (o < 14) ? 0 : (o < 28) ? 1 : (o < 42) ? 2 : 3;
    int j = o - g * 14;                        // g3 base is 42 = 3*14, works
    float v = (o < NLOC) ? lw[o * CC + c] : sw[(o - NLOC) * CC + c];
    wT3[(size_t)g * CC * GSTRIDE + c * GSTRIDE + j] = v;
}

// ---------------------------------------------------------------------------
// Kernel 2: anchors (55296, 4), closed form, f64 to match numpy.
// ---------------------------------------------------------------------------
__global__ void anchors_kernel(float* __restrict__ out3) {
    int t = blockIdx.x * 256 + threadIdx.x;   // over HW*NA
    if (t >= HW * NA) return;
    int a   = t % NA;
    int rem = t / NA;
    int h = rem / WW, w = rem % WW;
    int ri = a / 3, si = a % 3;
    const double ratios[3] = {0.5, 1.0, 2.0};
    const double scales[3] = {8.0, 16.0, 32.0};
    double ha = 16.0 * scales[si] * sqrt(ratios[ri]);
    double wa = 16.0 * scales[si] * sqrt(1.0 / ratios[ri]);
    float y1 = (float)(8.0 - ha * 0.5);
    float x1 = (float)(8.0 - wa * 0.5);
    float y2 = (float)(8.0 + ha * 0.5);
    float x2 = (float)(8.0 + wa * 0.5);
    float sy = (float)(h * 16);
    float sx = (float)(w * 16);
    float4 v = make_float4(sy + y1, sx + x1, sy + y2, sx + x2);
    *reinterpret_cast<float4*>(out3 + (size_t)t * 4) = v;
}

// ---------------------------------------------------------------------------
// Kernel 3: main. Block = 256 = 4 waves over the SAME 64 positions.
// Weight reads on scalar path (uniform base). Deep software pipeline on the
// x-loads: U=16 loads in flight while 16*NO FMAs retire -> latency hidden
// in-wave, independent of occupancy.
// ---------------------------------------------------------------------------
template<int NO>
__device__ __forceinline__ void rpn_accum(const float* __restrict__ xp,
                                          const float* __restrict__ wbase,
                                          float* acc) {
    constexpr int U = 16;
    #pragma unroll
    for (int o = 0; o < NO; ++o) acc[o] = 0.0f;

    float xv[U];
    #pragma unroll
    for (int u = 0; u < U; ++u) xv[u] = xp[(size_t)u * HW];

    #pragma unroll 1
    for (int cb = 0; cb < CC - U; cb += U) {
        float xn[U];
        #pragma unroll
        for (int u = 0; u < U; ++u)
            xn[u] = xp[(size_t)(cb + U + u) * HW];     // next batch in flight
        #pragma unroll
        for (int u = 0; u < U; ++u) {
            const float* wr = wbase + (size_t)(cb + u) * GSTRIDE;
            #pragma unroll
            for (int o = 0; o < NO; ++o)
                acc[o] = fmaf(xv[u], wr[o], acc[o]);
        }
        #pragma unroll
        for (int u = 0; u < U; ++u) xv[u] = xn[u];
    }
    #pragma unroll
    for (int u = 0; u < U; ++u) {                      // epilogue batch
        const float* wr = wbase + (size_t)(CC - U + u) * GSTRIDE;
        #pragma unroll
        for (int o = 0; o < NO; ++o)
            acc[o] = fmaf(xv[u], wr[o], acc[o]);
    }
}

__launch_bounds__(256)
__global__ void rpn_main_kernel(const float* __restrict__ x,
                                const float* __restrict__ wT3,
                                const float* __restrict__ lb,
                                const float* __restrict__ sb,
                                float* __restrict__ out0,   // rpn_loc
                                float* __restrict__ out1,   // rpn_score
                                float* __restrict__ out2) { // rpn_fg_scores
    int lane = threadIdx.x & 63;
    int og   = __builtin_amdgcn_readfirstlane(threadIdx.x >> 6); // uniform
    int p    = blockIdx.x * 64 + lane;           // position in [0, NN*HW)
    int n    = p / HW;
    int rem  = p % HW;
    const float* xp    = x + (size_t)n * CC * HW + rem;
    const float* wbase = wT3 + (size_t)og * CC * GSTRIDE;

    if (og == 3) {
        // scores 6..17
        float acc[12];
        rpn_accum<12>(xp, wbase, acc);
        float sc[12];
        size_t base1 = (size_t)p * NSC;
        #pragma unroll
        for (int j = 0; j < 12; ++j) {
            sc[j] = acc[j] + sb[6 + j];
            out1[base1 + 6 + j] = sc[j];
        }
        size_t base2 = (size_t)p * NA;
        #pragma unroll
        for (int a = 0; a < 6; ++a) {
            float d = sc[2 * a] - sc[2 * a + 1];
            out2[base2 + 3 + a] = 1.0f / (1.0f + __expf(d));
        }
    } else if (og == 2) {
        // loc 28..35 + scores 0..5
        float acc[14];
        rpn_accum<14>(xp, wbase, acc);
        size_t base0 = (size_t)p * NLOC + 28;
        #pragma unroll
        for (int j = 0; j < 8; ++j)
            out0[base0 + j] = acc[j] + lb[28 + j];
        float sc[6];
        size_t base1 = (size_t)p * NSC;
        #pragma unroll
        for (int j = 0; j < 6; ++j) {
            sc[j] = acc[8 + j] + sb[j];
            out1[base1 + j] = sc[j];
        }
        size_t base2 = (size_t)p * NA;
        #pragma unroll
        for (int a = 0; a < 3; ++a) {
            float d = sc[2 * a] - sc[2 * a + 1];
            out2[base2 + a] = 1.0f / (1.0f + __expf(d));
        }
    } else {
        // loc 14*og .. 14*og+13
        float acc[14];
        rpn_accum<14>(xp, wbase, acc);
        int ob = og * 14;
        size_t base0 = (size_t)p * NLOC + ob;
        #pragma unroll
        for (int j = 0; j < 14; ++j)
            out0[base0 + j] = acc[j] + lb[ob + j];
    }
}

extern "C" void kernel_launch(void* const* d_in, const int* in_sizes, int n_in,
                              void* d_out, int out_size, void* d_ws, size_t ws_size,
                              hipStream_t stream) {
    const float* x  = (const float*)d_in[0];
    const float* lw = (const float*)d_in[1];
    const float* lb = (const float*)d_in[2];
    const float* sw = (const float*)d_in[3];
    const float* sb = (const float*)d_in[4];

    float* out0 = (float*)d_out;                          // (16, 55296, 4)
    float* out1 = out0 + (size_t)NN * HW * NLOC;          // (16, 64, 96, 18)
    float* out2 = out1 + (size_t)NN * HW * NSC;           // (16, 55296)
    float* out3 = out2 + (size_t)NN * HW * NA;            // (55296, 4)

    float* wT3 = (float*)d_ws;   // 4*CC*16 floats = 128 KB

    int grid_t = (CC * 54 + 255) / 256;
    transpose_w_kernel<<<grid_t, 256, 0, stream>>>(lw, sw, wT3);

    int grid_a = (HW * NA + 255) / 256;
    anchors_kernel<<<grid_a, 256, 0, stream>>>(out3);

    int grid_m = NN * HW / 64;   // 1536 blocks * 4 waves
    rpn_main_kernel<<<grid_m, 256, 0, stream>>>(x, wT3, lb, sb, out0, out1, out2);
}

// Round 5
// 137.033 us; speedup vs baseline: 1.3516x; 1.3516x over previous
//
#include <hip/hip_runtime.h>
#include <math.h>

#define CC 512
#define HH 64
#define WW 96
#define NN 16
#define HW (HH*WW)        // 6144
#define NA 9
#define NLOC 36
#define NSC 18

// Output groups per wave: g0,g1,g2 = 14 loc-ish outputs, g3 = 12 (+2 zero pad)
//   g<3: o = g*14 + j (j<14);  g==3: o = 42 + j (j<12), j=12,13 are zero rows.
// wT3 layout: group g base = g*CC*16 floats; row c = 16 floats (64B aligned).
#define GSTRIDE 16

#define CHUNK 64
#define NCHUNK (CC / CHUNK)   // 8

// ---------------------------------------------------------------------------
// Kernel 1: scatter weights into padded per-group transposed layout.
// Pads (j >= group size) are ZERO so all waves can run a uniform 14-FMA loop.
// ---------------------------------------------------------------------------
__global__ void transpose_w_kernel(const float* __restrict__ lw,
                                   const float* __restrict__ sw,
                                   float* __restrict__ wT3) {
    int i = blockIdx.x * 256 + threadIdx.x;   // over 4*CC*16
    if (i >= 4 * CC * GSTRIDE) return;
    int g = i / (CC * GSTRIDE);
    int r = i % (CC * GSTRIDE);
    int c = r / GSTRIDE;
    int j = r % GSTRIDE;
    int lim = (g == 3) ? 12 : 14;
    float v = 0.0f;
    if (j < lim) {
        int o = g * 14 + j;                    // g3: 42 + j
        v = (o < NLOC) ? lw[o * CC + c] : sw[(o - NLOC) * CC + c];
    }
    wT3[i] = v;
}

// ---------------------------------------------------------------------------
// Kernel 2: anchors (55296, 4), closed form, f64 to match numpy.
// ---------------------------------------------------------------------------
__global__ void anchors_kernel(float* __restrict__ out3) {
    int t = blockIdx.x * 256 + threadIdx.x;   // over HW*NA
    if (t >= HW * NA) return;
    int a   = t % NA;
    int rem = t / NA;
    int h = rem / WW, w = rem % WW;
    int ri = a / 3, si = a % 3;
    const double ratios[3] = {0.5, 1.0, 2.0};
    const double scales[3] = {8.0, 16.0, 32.0};
    double ha = 16.0 * scales[si] * sqrt(ratios[ri]);
    double wa = 16.0 * scales[si] * sqrt(1.0 / ratios[ri]);
    float y1 = (float)(8.0 - ha * 0.5);
    float x1 = (float)(8.0 - wa * 0.5);
    float y2 = (float)(8.0 + ha * 0.5);
    float x2 = (float)(8.0 + wa * 0.5);
    float sy = (float)(h * 16);
    float sx = (float)(w * 16);
    float4 v = make_float4(sy + y1, sx + x1, sy + y2, sx + x2);
    *reinterpret_cast<float4*>(out3 + (size_t)t * 4) = v;
}

// ---------------------------------------------------------------------------
// Kernel 3: main. Block = 256 = 4 waves over the SAME 64 positions.
// x staged chunk-by-chunk into LDS ONCE per block (each wave stages 16 of 64
// channels), double-buffered; all 4 waves consume via ds_read_b32 (stride-1
// -> 2-way bank alias, free). Weights on scalar path (uniform base).
// T14 split: issue next-chunk loads -> compute current chunk -> ds_write ->
// barrier, so HBM latency hides under ~2200 cyc of chunk compute.
// ---------------------------------------------------------------------------
__launch_bounds__(256)
__global__ void rpn_main_kernel(const float* __restrict__ x,
                                const float* __restrict__ wT3,
                                const float* __restrict__ lb,
                                const float* __restrict__ sb,
                                float* __restrict__ out0,   // rpn_loc
                                float* __restrict__ out1,   // rpn_score
                                float* __restrict__ out2) { // rpn_fg_scores
    __shared__ float buf[2][CHUNK * 64];

    int lane = threadIdx.x & 63;
    int og   = __builtin_amdgcn_readfirstlane(threadIdx.x >> 6); // uniform
    int p    = blockIdx.x * 64 + lane;           // position in [0, NN*HW)
    int n    = p / HW;
    int rem  = p % HW;
    const float* xp    = x + (size_t)n * CC * HW + rem;
    const float* wbase = wT3 + (size_t)og * CC * GSTRIDE;

    float acc[14];
    #pragma unroll
    for (int o = 0; o < 14; ++o) acc[o] = 0.0f;

    float st[16];
    // prologue: stage chunk 0 (this wave's 16 channels)
    #pragma unroll
    for (int u = 0; u < 16; ++u)
        st[u] = xp[(size_t)(og * 16 + u) * HW];
    #pragma unroll
    for (int u = 0; u < 16; ++u)
        buf[0][(og * 16 + u) * 64 + lane] = st[u];
    __syncthreads();

    #pragma unroll 1
    for (int t = 0; t < NCHUNK; ++t) {
        int cb = t * CHUNK;
        // issue next chunk's global loads early (latency hides under compute)
        if (t + 1 < NCHUNK) {
            #pragma unroll
            for (int u = 0; u < 16; ++u)
                st[u] = xp[(size_t)(cb + CHUNK + og * 16 + u) * HW];
        }
        // compute current chunk from LDS
        const float* bp = buf[t & 1];
        #pragma unroll 8
        for (int c = 0; c < CHUNK; ++c) {
            float xv = bp[c * 64 + lane];
            const float* wr = wbase + (size_t)(cb + c) * GSTRIDE; // SGPR base
            #pragma unroll
            for (int o = 0; o < 14; ++o)
                acc[o] = fmaf(xv, wr[o], acc[o]);
        }
        // write staged regs to the other buffer, then barrier
        if (t + 1 < NCHUNK) {
            #pragma unroll
            for (int u = 0; u < 16; ++u)
                buf[(t + 1) & 1][(og * 16 + u) * 64 + lane] = st[u];
        }
        __syncthreads();
    }

    // ---------------- epilogue ----------------
    if (og == 3) {
        // scores 6..17 (acc[0..11]; acc[12..13] are zero-pad)
        float sc[12];
        size_t base1 = (size_t)p * NSC;
        #pragma unroll
        for (int j = 0; j < 12; ++j) {
            sc[j] = acc[j] + sb[6 + j];
            out1[base1 + 6 + j] = sc[j];
        }
        size_t base2 = (size_t)p * NA;
        #pragma unroll
        for (int a = 0; a < 6; ++a) {
            float d = sc[2 * a] - sc[2 * a + 1];
            out2[base2 + 3 + a] = 1.0f / (1.0f + __expf(d));
        }
    } else if (og == 2) {
        // loc 28..35 + scores 0..5
        size_t base0 = (size_t)p * NLOC + 28;
        #pragma unroll
        for (int j = 0; j < 8; ++j)
            out0[base0 + j] = acc[j] + lb[28 + j];
        float sc[6];
        size_t base1 = (size_t)p * NSC;
        #pragma unroll
        for (int j = 0; j < 6; ++j) {
            sc[j] = acc[8 + j] + sb[j];
            out1[base1 + j] = sc[j];
        }
        size_t base2 = (size_t)p * NA;
        #pragma unroll
        for (int a = 0; a < 3; ++a) {
            float d = sc[2 * a] - sc[2 * a + 1];
            out2[base2 + a] = 1.0f / (1.0f + __expf(d));
        }
    } else {
        // loc 14*og .. 14*og+13
        int ob = og * 14;
        size_t base0 = (size_t)p * NLOC + ob;
        #pragma unroll
        for (int j = 0; j < 14; ++j)
            out0[base0 + j] = acc[j] + lb[ob + j];
    }
}

extern "C" void kernel_launch(void* const* d_in, const int* in_sizes, int n_in,
                              void* d_out, int out_size, void* d_ws, size_t ws_size,
                              hipStream_t stream) {
    const float* x  = (const float*)d_in[0];
    const float* lw = (const float*)d_in[1];
    const float* lb = (const float*)d_in[2];
    const float* sw = (const float*)d_in[3];
    const float* sb = (const float*)d_in[4];

    float* out0 = (float*)d_out;                          // (16, 55296, 4)
    float* out1 = out0 + (size_t)NN * HW * NLOC;          // (16, 64, 96, 18)
    float* out2 = out1 + (size_t)NN * HW * NSC;           // (16, 55296)
    float* out3 = out2 + (size_t)NN * HW * NA;            // (55296, 4)

    float* wT3 = (float*)d_ws;   // 4*CC*16 floats = 128 KB

    int grid_t = (4 * CC * GSTRIDE + 255) / 256;
    transpose_w_kernel<<<grid_t, 256, 0, stream>>>(lw, sw, wT3);

    int grid_a = (HW * NA + 255) / 256;
    anchors_kernel<<<grid_a, 256, 0, stream>>>(out3);

    int grid_m = NN * HW / 64;   // 1536 blocks * 4 waves
    rpn_main_kernel<<<grid_m, 256, 0, stream>>>(x, wT3, lb, sb, out0, out1, out2);
}

// Round 6
// 78.001 us; speedup vs baseline: 2.3745x; 1.7568x over previous
//
#include <hip/hip_runtime.h>
#include <math.h>

#define CC 512
#define HH 64
#define WW 96
#define NN 16
#define HW (HH*WW)        // 6144
#define NA 9
#define NLOC 36
#define NSC 18
#define NO_PAD 64         // 54 outputs padded to 64 (4 N-tiles of 16)

typedef __attribute__((ext_vector_type(4))) float f32x4;
typedef __attribute__((ext_vector_type(8))) short s16x8;
typedef __attribute__((ext_vector_type(2))) unsigned int u32x2;

__device__ __host__ __forceinline__ unsigned short f2bf(float f) {
    unsigned u = __float_as_uint(f);
    return (unsigned short)((u + 0x7FFFu + ((u >> 16) & 1u)) >> 16);   // RNE
}

// ---------------------------------------------------------------------------
// Kernel 1: weights -> bf16, padded to 64 rows. wbf[o][c], c contiguous.
// ---------------------------------------------------------------------------
__global__ void prep_w_kernel(const float* __restrict__ lw,
                              const float* __restrict__ sw,
                              unsigned short* __restrict__ wbf) {
    int i = blockIdx.x * 256 + threadIdx.x;   // over 64*512
    if (i >= NO_PAD * CC) return;
    int o = i >> 9, c = i & 511;
    float v = 0.0f;
    if (o < NLOC) v = lw[o * CC + c];
    else if (o < 54) v = sw[(o - NLOC) * CC + c];
    wbf[i] = f2bf(v);
}

// ---------------------------------------------------------------------------
// Kernel 2: anchors (55296, 4), closed form, f64 to match numpy.
// ---------------------------------------------------------------------------
__global__ void anchors_kernel(float* __restrict__ out3) {
    int t = blockIdx.x * 256 + threadIdx.x;   // over HW*NA
    if (t >= HW * NA) return;
    int a   = t % NA;
    int rem = t / NA;
    int h = rem / WW, w = rem % WW;
    int ri = a / 3, si = a % 3;
    const double ratios[3] = {0.5, 1.0, 2.0};
    const double scales[3] = {8.0, 16.0, 32.0};
    double ha = 16.0 * scales[si] * sqrt(ratios[ri]);
    double wa = 16.0 * scales[si] * sqrt(1.0 / ratios[ri]);
    float y1 = (float)(8.0 - ha * 0.5);
    float x1 = (float)(8.0 - wa * 0.5);
    float y2 = (float)(8.0 + ha * 0.5);
    float x2 = (float)(8.0 + wa * 0.5);
    float sy = (float)(h * 16);
    float sx = (float)(w * 16);
    float4 v = make_float4(sy + y1, sx + x1, sy + y2, sx + x2);
    *reinterpret_cast<float4*>(out3 + (size_t)t * 4) = v;
}

// ---------------------------------------------------------------------------
// Kernel 3: MFMA main. Block = 256 = 4 waves; block owns 64 positions; wave w
// owns the 16-pos M-tile [w*16, w*16+16). K chunked by 64 channels, double-
// buffered LDS (2 x 8KB). x staged as bf16 in subtiled layout
// [c/4][p/16][c%4][p%16] (subtile = 4ch x 16pos = 128B): both ds_write_b64
// staging and ds_read_b64_tr_b16 A-fragment reads are exactly bank-balanced.
// B-fragments: 16B contiguous loads from bf16 weights (L1/L2-hot).
// C/D layout: col=lane&15 (output o), row=(lane>>4)*4+reg (position).
// ---------------------------------------------------------------------------
__launch_bounds__(256)
__global__ void rpn_mfma_kernel(const float* __restrict__ x,
                                const unsigned short* __restrict__ wbf,
                                const float* __restrict__ lb,
                                const float* __restrict__ sb,
                                float* __restrict__ out0,   // rpn_loc
                                float* __restrict__ out1,   // rpn_score
                                float* __restrict__ out2) { // rpn_fg_scores
    __shared__ unsigned short buf[2 * 4096];   // 16 KB

    const int tid  = threadIdx.x;
    const int lane = tid & 63;
    const int w    = tid >> 6;        // wave id = M-tile id
    const int col  = lane & 15;       // MFMA col (output) / A row (position)
    const int rgrp = lane >> 4;       // k-slice group

    const int pbase = blockIdx.x * 64;          // 64 | HW, so single n per block
    const int n     = pbase / HW;
    const int rem   = pbase % HW;
    const float* xb = x + (size_t)n * CC * HW + rem;

    const unsigned lds0 = (unsigned)(uintptr_t)buf;   // LDS byte offset (low 32 bits)
    // per-lane tr-read base: subtile (2*rgrp)*4 + w, lane offset (col)*8B
    const unsigned prec = 1024u * (unsigned)rgrp + 128u * (unsigned)w + 8u * (unsigned)col;

    f32x4 acc[4];
    #pragma unroll
    for (int nt = 0; nt < 4; ++nt) acc[nt] = (f32x4){0.f, 0.f, 0.f, 0.f};

    // ---- prologue: stage chunk 0 ----
    {
        float4 xv[4];
        #pragma unroll
        for (int i = 0; i < 4; ++i) {
            int q = i * 256 + tid; int c = q >> 4, pq = q & 15;
            xv[i] = *reinterpret_cast<const float4*>(xb + (size_t)c * HW + pq * 4);
        }
        #pragma unroll
        for (int i = 0; i < 4; ++i) {
            int q = i * 256 + tid; int c = q >> 4, pq = q & 15;
            int sub = (c >> 2) * 4 + (pq >> 2);
            u32x2 pk;
            pk.x = (unsigned)f2bf(xv[i].x) | ((unsigned)f2bf(xv[i].y) << 16);
            pk.y = (unsigned)f2bf(xv[i].z) | ((unsigned)f2bf(xv[i].w) << 16);
            *reinterpret_cast<u32x2*>(&buf[sub * 64 + (c & 3) * 16 + (pq & 3) * 4]) = pk;
        }
    }
    __syncthreads();

    #pragma unroll 1
    for (int t = 0; t < 8; ++t) {
        const int cb = t * 64;
        // T14: issue next chunk's global loads early
        float4 nx[4];
        if (t < 7) {
            #pragma unroll
            for (int i = 0; i < 4; ++i) {
                int q = i * 256 + tid; int c = q >> 4, pq = q & 15;
                nx[i] = *reinterpret_cast<const float4*>(xb + (size_t)(cb + 64 + c) * HW + pq * 4);
            }
        }
        // B fragments for this chunk (2 K-steps x 4 N-tiles), 16B contiguous
        s16x8 bfr[2][4];
        #pragma unroll
        for (int s = 0; s < 2; ++s)
            #pragma unroll
            for (int nt = 0; nt < 4; ++nt) {
                int o = nt * 16 + col;
                bfr[s][nt] = *reinterpret_cast<const s16x8*>(
                    wbf + (size_t)o * CC + cb + s * 32 + rgrp * 8);
            }
        // A fragments via hardware transpose-read
        unsigned ab = lds0 + (unsigned)((t & 1) * 8192) + prec;
        u32x2 a00, a01, a10, a11;
        asm volatile("ds_read_b64_tr_b16 %0, %1"             : "=v"(a00) : "v"(ab));
        asm volatile("ds_read_b64_tr_b16 %0, %1 offset:512"  : "=v"(a01) : "v"(ab));
        asm volatile("ds_read_b64_tr_b16 %0, %1 offset:4096" : "=v"(a10) : "v"(ab));
        asm volatile("ds_read_b64_tr_b16 %0, %1 offset:4608" : "=v"(a11) : "v"(ab));
        asm volatile("s_waitcnt lgkmcnt(0)" ::: "memory");
        __builtin_amdgcn_sched_barrier(0);   // rule #18: keep MFMA below the wait

        union { u32x2 q[2]; s16x8 v; } fa0, fa1;
        fa0.q[0] = a00; fa0.q[1] = a01;      // k = rgrp*8 + 0..7, K-step 0
        fa1.q[0] = a10; fa1.q[1] = a11;      // K-step 1

        #pragma unroll
        for (int nt = 0; nt < 4; ++nt)
            acc[nt] = __builtin_amdgcn_mfma_f32_16x16x32_bf16(fa0.v, bfr[0][nt], acc[nt], 0, 0, 0);
        #pragma unroll
        for (int nt = 0; nt < 4; ++nt)
            acc[nt] = __builtin_amdgcn_mfma_f32_16x16x32_bf16(fa1.v, bfr[1][nt], acc[nt], 0, 0, 0);

        // write next chunk to the other buffer
        if (t < 7) {
            #pragma unroll
            for (int i = 0; i < 4; ++i) {
                int q = i * 256 + tid; int c = q >> 4, pq = q & 15;
                int sub = (c >> 2) * 4 + (pq >> 2);
                u32x2 pk;
                pk.x = (unsigned)f2bf(nx[i].x) | ((unsigned)f2bf(nx[i].y) << 16);
                pk.y = (unsigned)f2bf(nx[i].z) | ((unsigned)f2bf(nx[i].w) << 16);
                *reinterpret_cast<u32x2*>(
                    &buf[((t + 1) & 1) * 4096 + sub * 64 + (c & 3) * 16 + (pq & 3) * 4]) = pk;
            }
        }
        __syncthreads();
    }

    // ---- epilogue: bias + stores + fg softmax (pairs live in lanes l, l^1) ----
    #pragma unroll
    for (int nt = 0; nt < 4; ++nt) {
        int o = nt * 16 + col;
        float bias = (o < NLOC) ? lb[o] : ((o < 54) ? sb[o - NLOC] : 0.0f);
        #pragma unroll
        for (int r = 0; r < 4; ++r) {
            float val  = acc[nt][r] + bias;
            float part = __shfl_xor(val, 1);           // partner score (o^1)
            int p = pbase + w * 16 + rgrp * 4 + r;     // global position
            if (o < NLOC) {
                out0[(size_t)p * NLOC + o] = val;
            } else if (o < 54) {
                int os = o - NLOC;
                out1[(size_t)p * NSC + os] = val;
                if ((os & 1) == 0)                     // even lane holds s0
                    out2[(size_t)p * NA + (os >> 1)] = 1.0f / (1.0f + __expf(val - part));
            }
        }
    }
}

extern "C" void kernel_launch(void* const* d_in, const int* in_sizes, int n_in,
                              void* d_out, int out_size, void* d_ws, size_t ws_size,
                              hipStream_t stream) {
    const float* x  = (const float*)d_in[0];
    const float* lw = (const float*)d_in[1];
    const float* lb = (const float*)d_in[2];
    const float* sw = (const float*)d_in[3];
    const float* sb = (const float*)d_in[4];

    float* out0 = (float*)d_out;                          // (16, 55296, 4)
    float* out1 = out0 + (size_t)NN * HW * NLOC;          // (16, 64, 96, 18)
    float* out2 = out1 + (size_t)NN * HW * NSC;           // (16, 55296)
    float* out3 = out2 + (size_t)NN * HW * NA;            // (55296, 4)

    unsigned short* wbf = (unsigned short*)d_ws;          // 64*512*2 = 64 KB

    int grid_w = (NO_PAD * CC + 255) / 256;               // 128
    prep_w_kernel<<<grid_w, 256, 0, stream>>>(lw, sw, wbf);

    int grid_a = (HW * NA + 255) / 256;                   // 216
    anchors_kernel<<<grid_a, 256, 0, stream>>>(out3);

    int grid_m = NN * HW / 64;                            // 1536
    rpn_mfma_kernel<<<grid_m, 256, 0, stream>>>(x, wbf, lb, sb, out0, out1, out2);
}

// Round 7
// 68.432 us; speedup vs baseline: 2.7065x; 1.1398x over previous
//
#include <hip/hip_runtime.h>
#include <math.h>

#define CC 512
#define HH 64
#define WW 96
#define NN 16
#define HW (HH*WW)        // 6144
#define NA 9
#define NLOC 36
#define NSC 18
#define NO_PAD 64         // 54 outputs padded to 64 (4 N-tiles of 16)

typedef __attribute__((ext_vector_type(4))) float f32x4;
typedef __attribute__((ext_vector_type(8))) short s16x8;
typedef __attribute__((ext_vector_type(2))) unsigned int u32x2;

__device__ __host__ __forceinline__ unsigned short f2bf(float f) {
    unsigned u = __float_as_uint(f);
    return (unsigned short)((u + 0x7FFFu + ((u >> 16) & 1u)) >> 16);   // RNE
}

// ---------------------------------------------------------------------------
// Kernel 1 (fused prep): blocks 0..127 convert weights to bf16 (padded to 64
// rows, wbf[o][c]); blocks 128..343 write the anchor grid (f64, matches numpy).
// ---------------------------------------------------------------------------
__global__ void prep_kernel(const float* __restrict__ lw,
                            const float* __restrict__ sw,
                            unsigned short* __restrict__ wbf,
                            float* __restrict__ out3) {
    int b = blockIdx.x;
    if (b < 128) {
        int i = b * 256 + threadIdx.x;        // over 64*512
        int o = i >> 9, c = i & 511;
        float v = 0.0f;
        if (o < NLOC) v = lw[o * CC + c];
        else if (o < 54) v = sw[(o - NLOC) * CC + c];
        wbf[i] = f2bf(v);
    } else {
        int t = (b - 128) * 256 + threadIdx.x;   // over HW*NA
        if (t >= HW * NA) return;
        int a   = t % NA;
        int rem = t / NA;
        int h = rem / WW, w = rem % WW;
        int ri = a / 3, si = a % 3;
        const double ratios[3] = {0.5, 1.0, 2.0};
        const double scales[3] = {8.0, 16.0, 32.0};
        double ha = 16.0 * scales[si] * sqrt(ratios[ri]);
        double wa = 16.0 * scales[si] * sqrt(1.0 / ratios[ri]);
        float y1 = (float)(8.0 - ha * 0.5);
        float x1 = (float)(8.0 - wa * 0.5);
        float y2 = (float)(8.0 + ha * 0.5);
        float x2 = (float)(8.0 + wa * 0.5);
        float sy = (float)(h * 16);
        float sx = (float)(w * 16);
        float4 v = make_float4(sy + y1, sx + x1, sy + y2, sx + x2);
        *reinterpret_cast<float4*>(out3 + (size_t)t * 4) = v;
    }
}

// ---------------------------------------------------------------------------
// Kernel 2: MFMA main. Block = 256 = 4 waves; block owns 64 positions; wave w
// owns the 16-pos M-tile. K chunked by 64 channels, TRIPLE-buffered LDS
// (3 x 8KB), prefetch depth 2: round t issues chunk t+2's global loads,
// ds_writes chunk t+1 (loaded last round -> vmcnt naturally counted), computes
// chunk t. Raw s_barrier + explicit lgkmcnt(0) so prefetch loads stay in
// flight across the barrier (T3/T4; __syncthreads would drain vmcnt(0)).
// x staged as bf16, subtiled [c/4][p/16][c%4][p%16] -> ds_write_b64 and
// ds_read_b64_tr_b16 both bank-balanced. B-frags: 16B loads, L1-hot.
// ---------------------------------------------------------------------------
__launch_bounds__(256)
__global__ void rpn_mfma_kernel(const float* __restrict__ x,
                                const unsigned short* __restrict__ wbf,
                                const float* __restrict__ lb,
                                const float* __restrict__ sb,
                                float* __restrict__ out0,   // rpn_loc
                                float* __restrict__ out1,   // rpn_score
                                float* __restrict__ out2) { // rpn_fg_scores
    __shared__ unsigned short buf[3 * 4096];   // 24 KB

    const int tid  = threadIdx.x;
    const int lane = tid & 63;
    const int w    = tid >> 6;        // wave id = M-tile id
    const int col  = lane & 15;
    const int rgrp = lane >> 4;

    const int pbase = blockIdx.x * 64;          // 64 | HW -> single n per block
    const int n     = pbase / HW;
    const int rem   = pbase % HW;
    const float* xb = x + (size_t)n * CC * HW + rem;

    // per-thread staging geometry (constant across rounds)
    size_t goff[4];  int loff[4];
    #pragma unroll
    for (int i = 0; i < 4; ++i) {
        int q = i * 256 + tid, c = q >> 4, pq = q & 15;
        goff[i] = (size_t)c * HW + pq * 4;
        loff[i] = ((c >> 2) * 4 + (pq >> 2)) * 64 + (c & 3) * 16 + (pq & 3) * 4;
    }

    const unsigned lds0 = (unsigned)(uintptr_t)buf;
    const unsigned prec = 1024u * (unsigned)rgrp + 128u * (unsigned)w + 8u * (unsigned)col;

    f32x4 acc[4];
    #pragma unroll
    for (int nt = 0; nt < 4; ++nt) acc[nt] = (f32x4){0.f, 0.f, 0.f, 0.f};

    // ---- prologue: chunk0 -> buf[0]; chunk1 loads in flight ----
    float4 pend[4], nx[4];
    #pragma unroll
    for (int i = 0; i < 4; ++i)
        pend[i] = *reinterpret_cast<const float4*>(xb + goff[i]);           // chunk 0
    #pragma unroll
    for (int i = 0; i < 4; ++i)
        nx[i] = *reinterpret_cast<const float4*>(xb + (size_t)64 * HW + goff[i]); // chunk 1
    #pragma unroll
    for (int i = 0; i < 4; ++i) {
        u32x2 pk;
        pk.x = (unsigned)f2bf(pend[i].x) | ((unsigned)f2bf(pend[i].y) << 16);
        pk.y = (unsigned)f2bf(pend[i].z) | ((unsigned)f2bf(pend[i].w) << 16);
        *reinterpret_cast<u32x2*>(&buf[loff[i]]) = pk;
    }
    #pragma unroll
    for (int i = 0; i < 4; ++i) pend[i] = nx[i];
    asm volatile("s_waitcnt lgkmcnt(0)" ::: "memory");
    __builtin_amdgcn_s_barrier();

    #pragma unroll 1
    for (int t = 0; t < 8; ++t) {
        const int cb = t * 64;
        // issue chunk t+2 loads (stay in flight across this AND next barrier)
        if (t < 6) {
            #pragma unroll
            for (int i = 0; i < 4; ++i)
                nx[i] = *reinterpret_cast<const float4*>(
                    xb + (size_t)(cb + 128) * HW + goff[i]);
        }
        // ds_write chunk t+1 (its loads finished ~1 round ago -> counted vmcnt)
        if (t < 7) {
            unsigned short* bw = &buf[((t + 1) % 3) * 4096];
            #pragma unroll
            for (int i = 0; i < 4; ++i) {
                u32x2 pk;
                pk.x = (unsigned)f2bf(pend[i].x) | ((unsigned)f2bf(pend[i].y) << 16);
                pk.y = (unsigned)f2bf(pend[i].z) | ((unsigned)f2bf(pend[i].w) << 16);
                *reinterpret_cast<u32x2*>(&bw[loff[i]]) = pk;
            }
        }
        // B fragments (2 K-steps x 4 N-tiles), 16B contiguous, L1-hot
        s16x8 bfr[2][4];
        #pragma unroll
        for (int s = 0; s < 2; ++s)
            #pragma unroll
            for (int nt = 0; nt < 4; ++nt) {
                int o = nt * 16 + col;
                bfr[s][nt] = *reinterpret_cast<const s16x8*>(
                    wbf + (size_t)o * CC + cb + s * 32 + rgrp * 8);
            }
        // A fragments via hardware transpose-read from buf[t%3]
        unsigned ab = lds0 + (unsigned)((t % 3) * 8192) + prec;
        u32x2 a00, a01, a10, a11;
        asm volatile("ds_read_b64_tr_b16 %0, %1"             : "=v"(a00) : "v"(ab));
        asm volatile("ds_read_b64_tr_b16 %0, %1 offset:512"  : "=v"(a01) : "v"(ab));
        asm volatile("ds_read_b64_tr_b16 %0, %1 offset:4096" : "=v"(a10) : "v"(ab));
        asm volatile("ds_read_b64_tr_b16 %0, %1 offset:4608" : "=v"(a11) : "v"(ab));
        asm volatile("s_waitcnt lgkmcnt(0)" ::: "memory");
        __builtin_amdgcn_sched_barrier(0);   // rule #18

        union { u32x2 q[2]; s16x8 v; } fa0, fa1;
        fa0.q[0] = a00; fa0.q[1] = a01;
        fa1.q[0] = a10; fa1.q[1] = a11;

        #pragma unroll
        for (int nt = 0; nt < 4; ++nt)
            acc[nt] = __builtin_amdgcn_mfma_f32_16x16x32_bf16(fa0.v, bfr[0][nt], acc[nt], 0, 0, 0);
        #pragma unroll
        for (int nt = 0; nt < 4; ++nt)
            acc[nt] = __builtin_amdgcn_mfma_f32_16x16x32_bf16(fa1.v, bfr[1][nt], acc[nt], 0, 0, 0);

        // rotate staging regs; raw barrier (ds ops already drained above)
        #pragma unroll
        for (int i = 0; i < 4; ++i) pend[i] = nx[i];
        asm volatile("s_waitcnt lgkmcnt(0)" ::: "memory");
        __builtin_amdgcn_s_barrier();
    }

    // ---- epilogue: bias + stores + fg softmax (score pairs in lanes l, l^1) ----
    #pragma unroll
    for (int nt = 0; nt < 4; ++nt) {
        int o = nt * 16 + col;
        float bias = (o < NLOC) ? lb[o] : ((o < 54) ? sb[o - NLOC] : 0.0f);
        #pragma unroll
        for (int r = 0; r < 4; ++r) {
            float val  = acc[nt][r] + bias;
            float part = __shfl_xor(val, 1);
            int p = pbase + w * 16 + rgrp * 4 + r;
            if (o < NLOC) {
                out0[(size_t)p * NLOC + o] = val;
            } else if (o < 54) {
                int os = o - NLOC;
                out1[(size_t)p * NSC + os] = val;
                if ((os & 1) == 0)
                    out2[(size_t)p * NA + (os >> 1)] = 1.0f / (1.0f + __expf(val - part));
            }
        }
    }
}

extern "C" void kernel_launch(void* const* d_in, const int* in_sizes, int n_in,
                              void* d_out, int out_size, void* d_ws, size_t ws_size,
                              hipStream_t stream) {
    const float* x  = (const float*)d_in[0];
    const float* lw = (const float*)d_in[1];
    const float* lb = (const float*)d_in[2];
    const float* sw = (const float*)d_in[3];
    const float* sb = (const float*)d_in[4];

    float* out0 = (float*)d_out;                          // (16, 55296, 4)
    float* out1 = out0 + (size_t)NN * HW * NLOC;          // (16, 64, 96, 18)
    float* out2 = out1 + (size_t)NN * HW * NSC;           // (16, 55296)
    float* out3 = out2 + (size_t)NN * HW * NA;            // (55296, 4)

    unsigned short* wbf = (unsigned short*)d_ws;          // 64*512*2 = 64 KB

    prep_kernel<<<344, 256, 0, stream>>>(lw, sw, wbf, out3);

    int grid_m = NN * HW / 64;                            // 1536
    rpn_mfma_kernel<<<grid_m, 256, 0, stream>>>(x, wbf, lb, sb, out0, out1, out2);
}